// Round 1
// baseline (1008.073 us; speedup 1.0000x reference)
//
#include <hip/hip_runtime.h>
#include <hip/hip_bf16.h>

#define CIN 512
#define COUT 512
#define BATCH 16
#define NP 3844          // 62*62 output positions
#define OW 62

#define W_MUL_DENSE 0.044194173824159216f
#define W_MUL_CONV  0.014731391274719736f

using short8  = __attribute__((ext_vector_type(8))) short;
using floatx4 = __attribute__((ext_vector_type(4))) float;
using uintx4  = __attribute__((ext_vector_type(4))) unsigned int;

__device__ __forceinline__ unsigned short f2bfu(float f) {
    unsigned u = __builtin_bit_cast(unsigned, f);
    u += 0x7FFFu + ((u >> 16) & 1u);   // round-to-nearest-even
    return (unsigned short)(u >> 16);
}

// ---------------- prep kernels ----------------

// s[b,c] = dot(y[b,:], dw[c,:]) * W_MUL_DENSE + db[c]
__global__ void emc_style_kernel(const float* __restrict__ y, const float* __restrict__ dw,
                                 const float* __restrict__ db, float* __restrict__ s) {
    int idx = blockIdx.x * 256 + threadIdx.x;       // 16*512
    int b = idx >> 9, c = idx & 511;
    const float4* yb = (const float4*)(y + b * 512);
    const float4* wc = (const float4*)(dw + c * 512);
    float acc = 0.f;
#pragma unroll 4
    for (int l = 0; l < 128; ++l) {
        float4 a = yb[l], w4 = wc[l];
        acc += a.x * w4.x + a.y * w4.y + a.z * w4.z + a.w * w4.w;
    }
    s[idx] = acc * W_MUL_DENSE + db[c];
}

// wsq[o*512+i] = sum_kpos w[o,i,kpos]^2
__global__ void emc_wsq_kernel(const float* __restrict__ w, float* __restrict__ wsq) {
    int idx = blockIdx.x * 256 + threadIdx.x;       // 512*512
    const float* p = w + (size_t)idx * 9;
    float a = 0.f;
#pragma unroll
    for (int j = 0; j < 9; ++j) a += p[j] * p[j];
    wsq[idx] = a;
}

// d[b,o] = rsqrt(WMC^2 * sum_i s[b,i]^2 * wsq[o,i] + 1e-8)
__global__ void emc_demod_kernel(const float* __restrict__ s, const float* __restrict__ wsq,
                                 float* __restrict__ d) {
    int idx = blockIdx.x * 256 + threadIdx.x;       // 16*512
    int b = idx >> 9, o = idx & 511;
    const float4* sb = (const float4*)(s + b * 512);
    const float4* wo = (const float4*)(wsq + o * 512);
    float acc = 0.f;
#pragma unroll 4
    for (int l = 0; l < 128; ++l) {
        float4 a = sb[l], c = wo[l];
        acc += a.x * a.x * c.x + a.y * a.y * c.y + a.z * a.z * c.z + a.w * a.w * c.w;
    }
    d[idx] = rsqrtf(W_MUL_CONV * W_MUL_CONV * acc + 1e-8f);
}

// wb[(o*9+kpos)*512 + i] = bf16(w[(o*512+i)*9 + kpos])   (A matrix, K-contig in i per kpos)
__global__ void emc_wrepack_kernel(const float* __restrict__ w, unsigned short* __restrict__ wb) {
    int idx = blockIdx.x * 256 + threadIdx.x;       // 512*9*512
    int i = idx & 511;
    int r = idx >> 9;
    int kpos = r % 9;
    int o = r / 9;
    wb[idx] = f2bfu(w[(size_t)(o * 512 + i) * 9 + kpos]);
}

// ---------------- main conv kernel ----------------
// Implicit GEMM per batch: C[o,p] = sum_{kpos,i} W[o,kpos,i] * (s[b,i]*x[b,i,py+kh,px+kw])
// BM=128 (o), BN=128 (p), BK=32 (i), K-loop = 9 kpos * 16 i-steps = 144.
// out[b,o,p] = C[o,p] * WMC * d[b,o]

__global__ __launch_bounds__(256, 2) void emc_conv_kernel(
    const float* __restrict__ x, const unsigned short* __restrict__ wb,
    const float* __restrict__ sv, const float* __restrict__ dv,
    float* __restrict__ out) {

    __shared__ __align__(16) char smA[2][128 * 80];
    __shared__ __align__(16) char smB[2][128 * 80];
    __shared__ float s_s[512];
    __shared__ float s_d[128];

    int bid = blockIdx.x;
    int b = bid / 124;              // 124 tiles per batch = 4 o-tiles * 31 p-tiles
    int t = bid - b * 124;
    int pt = t >> 2;
    int ot = t & 3;
    int oB = ot * 128, pB = pt * 128;

    int tid = threadIdx.x;
    int lane = tid & 63;

    // stage style + demod vectors
    s_s[tid]       = sv[b * 512 + tid];
    s_s[tid + 256] = sv[b * 512 + 256 + tid];
    if (tid < 128) s_d[tid] = dv[b * 512 + oB + tid];

    // ---- B staging coords (thread owns one p, two k's per k-quad) ----
    int p_loc = tid & 127;
    int khalf = tid >> 7;            // 0/1
    int p_glob = pB + p_loc;
    int pvalid = p_glob < NP;
    int pc = pvalid ? p_glob : 0;
    int py = pc / OW;
    int px = pc - py * OW;
    const float* xbase = x + (size_t)b * (512 * 4096) + py * 64 + px;
    int bswz = (p_loc >> 3) & 3;

    // ---- A staging coords (thread owns half a row of 64B) ----
    int o_loc = tid >> 1;
    int ahalf = tid & 1;
    const unsigned short* abase = wb + (size_t)(oB + o_loc) * (9 * 512) + ahalf * 16;
    int aswz = (o_loc >> 3) & 3;
    int abyte0 = o_loc * 80 + (((ahalf * 2)     ^ aswz) << 4);
    int abyte1 = o_loc * 80 + (((ahalf * 2 + 1) ^ aswz) << 4);

    // ---- compute coords ----
    int wv = tid >> 6;
    int wr = wv >> 1, wc = wv & 1;   // 2x2 wave grid, each wave 64x64 output
    int fr = lane & 15, q = lane >> 4;
    int aoff[4], boff[4];
#pragma unroll
    for (int m = 0; m < 4; ++m) {
        int o = wr * 64 + m * 16 + fr;
        aoff[m] = o * 80 + ((q ^ ((o >> 3) & 3)) << 4);
    }
#pragma unroll
    for (int n = 0; n < 4; ++n) {
        int p = wc * 64 + n * 16 + fr;
        boff[n] = p * 80 + ((q ^ ((p >> 3) & 3)) << 4);
    }

    floatx4 acc[4][4];
#pragma unroll
    for (int m = 0; m < 4; ++m)
#pragma unroll
        for (int n = 0; n < 4; ++n) acc[m][n] = floatx4{0.f, 0.f, 0.f, 0.f};

    __syncthreads();   // s_s ready

    uintx4 areg0, areg1;
    float breg[16];

    auto STAGE = [&](int st) {
        int kpos = st >> 4;
        int i0 = (st & 15) << 5;
        const unsigned short* ap = abase + kpos * 512 + i0;
        areg0 = *(const uintx4*)(ap);
        areg1 = *(const uintx4*)(ap + 8);
        int kh = kpos / 3;
        int kw = kpos - kh * 3;
        const float* xp = xbase + (kh * 64 + kw);
#pragma unroll
        for (int j = 0; j < 8; ++j) {
            int k0 = j * 4 + khalf * 2;
            int i = i0 + k0;
            float v0 = 0.f, v1 = 0.f;
            if (pvalid) {
                v0 = xp[(size_t)i * 4096] * s_s[i];
                v1 = xp[(size_t)(i + 1) * 4096] * s_s[i + 1];
            }
            breg[2 * j] = v0;
            breg[2 * j + 1] = v1;
        }
    };

    auto WRITE = [&](int buf) {
        char* A = smA[buf];
        *(uintx4*)(A + abyte0) = areg0;
        *(uintx4*)(A + abyte1) = areg1;
        char* brow = smB[buf] + p_loc * 80;
#pragma unroll
        for (int j = 0; j < 8; ++j) {
            int k0 = j * 4 + khalf * 2;
            unsigned pk = (unsigned)f2bfu(breg[2 * j]) | ((unsigned)f2bfu(breg[2 * j + 1]) << 16);
            *(unsigned*)(brow + ((((k0 >> 3) ^ bswz) << 4) | ((k0 & 7) << 1))) = pk;
        }
    };

    auto COMPUTE = [&](int buf) {
        const char* A = smA[buf];
        const char* Bm = smB[buf];
        short8 af[4], bfv[4];
#pragma unroll
        for (int m = 0; m < 4; ++m) af[m] = *(const short8*)(A + aoff[m]);
#pragma unroll
        for (int n = 0; n < 4; ++n) bfv[n] = *(const short8*)(Bm + boff[n]);
#pragma unroll
        for (int m = 0; m < 4; ++m)
#pragma unroll
            for (int n = 0; n < 4; ++n)
                acc[m][n] = __builtin_amdgcn_mfma_f32_16x16x32_bf16(af[m], bfv[n], acc[m][n], 0, 0, 0);
    };

    STAGE(0);
    WRITE(0);
    __syncthreads();
    int cur = 0;
    for (int st = 0; st < 144; ++st) {
        if (st < 143) STAGE(st + 1);
        COMPUTE(cur);
        if (st < 143) WRITE(cur ^ 1);
        __syncthreads();
        cur ^= 1;
    }

    // epilogue: scale by WMC * d[b,o], store fp32
    size_t outb = (size_t)b * 512 * NP;
#pragma unroll
    for (int m = 0; m < 4; ++m) {
        int orow0 = wr * 64 + m * 16 + q * 4;
#pragma unroll
        for (int r = 0; r < 4; ++r) {
            int o_l = orow0 + r;
            float scale = W_MUL_CONV * s_d[o_l];
            size_t rb = outb + (size_t)(oB + o_l) * NP;
#pragma unroll
            for (int n = 0; n < 4; ++n) {
                int p = pB + wc * 64 + n * 16 + fr;
                if (p < NP) out[rb + p] = acc[m][n][r] * scale;
            }
        }
    }
}

// ---------------- launch ----------------
extern "C" void kernel_launch(void* const* d_in, const int* in_sizes, int n_in,
                              void* d_out, int out_size, void* d_ws, size_t ws_size,
                              hipStream_t stream) {
    const float* x  = (const float*)d_in[0];   // [16,512,64,64]
    const float* y  = (const float*)d_in[1];   // [16,512]
    const float* dw = (const float*)d_in[2];   // [512,512]
    const float* db = (const float*)d_in[3];   // [512]
    const float* w  = (const float*)d_in[4];   // [512,512,3,3]
    float* out = (float*)d_out;                // [16,512,62,62]

    char* ws = (char*)d_ws;
    float* s_  = (float*)ws;                               // 16*512 f32   (32 KB)
    float* d_  = (float*)(ws + 32768);                     // 16*512 f32   (32 KB)
    float* wsq = (float*)(ws + 65536);                     // 512*512 f32  (1 MB)
    unsigned short* wb = (unsigned short*)(ws + 65536 + 1048576);  // 512*9*512 bf16 (4.72 MB)

    emc_style_kernel<<<32, 256, 0, stream>>>(y, dw, db, s_);
    emc_wsq_kernel<<<1024, 256, 0, stream>>>(w, wsq);
    emc_demod_kernel<<<32, 256, 0, stream>>>(s_, wsq, d_);
    emc_wrepack_kernel<<<9216, 256, 0, stream>>>(w, wb);
    emc_conv_kernel<<<16 * 124, 256, 0, stream>>>(x, wb, s_, d_, out);
}

// Round 2
// 401.320 us; speedup vs baseline: 2.5119x; 2.5119x over previous
//
#include <hip/hip_runtime.h>
#include <hip/hip_bf16.h>

#define CIN 512
#define COUT 512
#define BATCH 16
#define NP 3844          // 62*62 output positions
#define OW 62

#define W_MUL_DENSE 0.044194173824159216f
#define W_MUL_CONV  0.014731391274719736f

using short8  = __attribute__((ext_vector_type(8))) short;
using floatx4 = __attribute__((ext_vector_type(4))) float;
using uintx4  = __attribute__((ext_vector_type(4))) unsigned int;

__device__ __forceinline__ unsigned short f2bfu(float f) {
    unsigned u = __builtin_bit_cast(unsigned, f);
    u += 0x7FFFu + ((u >> 16) & 1u);   // round-to-nearest-even
    return (unsigned short)(u >> 16);
}

__device__ __forceinline__ void gload_lds16(const void* g, void* l) {
    __builtin_amdgcn_global_load_lds(
        (const __attribute__((address_space(1))) void*)g,
        (__attribute__((address_space(3))) void*)l, 16, 0, 0);
}

// ---------------- prep kernels (unchanged from R1) ----------------

__global__ void emc_style_kernel(const float* __restrict__ y, const float* __restrict__ dw,
                                 const float* __restrict__ db, float* __restrict__ s) {
    int idx = blockIdx.x * 256 + threadIdx.x;       // 16*512
    int b = idx >> 9, c = idx & 511;
    const float4* yb = (const float4*)(y + b * 512);
    const float4* wc = (const float4*)(dw + c * 512);
    float acc = 0.f;
#pragma unroll 4
    for (int l = 0; l < 128; ++l) {
        float4 a = yb[l], w4 = wc[l];
        acc += a.x * w4.x + a.y * w4.y + a.z * w4.z + a.w * w4.w;
    }
    s[idx] = acc * W_MUL_DENSE + db[c];
}

__global__ void emc_wsq_kernel(const float* __restrict__ w, float* __restrict__ wsq) {
    int idx = blockIdx.x * 256 + threadIdx.x;       // 512*512
    const float* p = w + (size_t)idx * 9;
    float a = 0.f;
#pragma unroll
    for (int j = 0; j < 9; ++j) a += p[j] * p[j];
    wsq[idx] = a;
}

__global__ void emc_demod_kernel(const float* __restrict__ s, const float* __restrict__ wsq,
                                 float* __restrict__ d) {
    int idx = blockIdx.x * 256 + threadIdx.x;       // 16*512
    int b = idx >> 9, o = idx & 511;
    const float4* sb = (const float4*)(s + b * 512);
    const float4* wo = (const float4*)(wsq + o * 512);
    float acc = 0.f;
#pragma unroll 4
    for (int l = 0; l < 128; ++l) {
        float4 a = sb[l], c = wo[l];
        acc += a.x * a.x * c.x + a.y * a.y * c.y + a.z * a.z * c.z + a.w * a.w * c.w;
    }
    d[idx] = rsqrtf(W_MUL_CONV * W_MUL_CONV * acc + 1e-8f);
}

// wb[(o*9+kpos)*512 + i] = bf16(w[(o*512+i)*9 + kpos])  (linear, K-contig in i per kpos)
__global__ void emc_wrepack_kernel(const float* __restrict__ w, unsigned short* __restrict__ wb) {
    int idx = blockIdx.x * 256 + threadIdx.x;       // 512*9*512
    int i = idx & 511;
    int r = idx >> 9;
    int kpos = r % 9;
    int o = r / 9;
    wb[idx] = f2bfu(w[(size_t)(o * 512 + i) * 9 + kpos]);
}

// ---------------- main conv kernel ----------------
// Tile: BM=128 (o) x strip of 2 output rows (124 p, padded to 128 lanes).
// B (x-halo) tile: [4 rows][64 cols][32 i] bf16 in 80B granules, staged once per
// i-tile, reused by all 9 kpos via shifted reads. A (weights) tile: 128x32 bf16
// per (kpos,i-tile), double-buffered via global_load_lds width-16.

__global__ __launch_bounds__(256, 3) void emc_conv_kernel(
    const float* __restrict__ x, const unsigned short* __restrict__ wb,
    const float* __restrict__ sv, const float* __restrict__ dv,
    float* __restrict__ out) {

    __shared__ __align__(16) unsigned short smA[2][128 * 32];   // 2 x 8 KB
    __shared__ __align__(16) unsigned short smB[260 * 40];      // 20.8 KB (granule = 40 shorts = 80B)
    __shared__ float s_s[512];
    __shared__ float s_d[128];

    // bijective XCD swizzle (gridDim = 1984, 1984 % 8 == 0)
    int orig = blockIdx.x;
    int cpx = gridDim.x >> 3;
    int bid = (orig & 7) * cpx + (orig >> 3);

    int b = bid / 124;
    int t = bid - b * 124;
    int ot = t & 3;
    int strip = t >> 2;
    int oB = ot * 128;
    int r0 = strip * 2;

    int tid = threadIdx.x;
    int lane = tid & 63;
    int wid = tid >> 6;

    s_s[tid]       = sv[b * 512 + tid];
    s_s[tid + 256] = sv[b * 512 + 256 + tid];
    if (tid < 128) s_d[tid] = dv[b * 512 + oB + tid];

    // ---- B staging ids: thread owns (row sr, col sc), 32 i per i-tile ----
    int sc = tid & 63;
    int sr = tid >> 6;
    const float* xrow = x + (size_t)b * (512 * 4096) + (r0 + sr) * 64 + sc;
    unsigned short* bg = smB + (sr * 64 + sc) * 40;

    // ---- A DMA ids: wave wid covers LDS chunks 2*wid, 2*wid+1 (1024B each) ----
    const unsigned short* asrc[2];
#pragma unroll
    for (int j = 0; j < 2; ++j)
        asrc[j] = wb + (size_t)(oB + (wid * 2 + j) * 16 + (lane >> 2)) * 4608 + (lane & 3) * 8;

    // ---- compute ids ----
    int frc = lane & 15, q = lane >> 4;
    int wr = wid >> 1, wc = wid & 1;    // wr: o-half, wc: output row within strip
    int aidx[4], bidx[4];
#pragma unroll
    for (int m = 0; m < 4; ++m) aidx[m] = (wr * 64 + m * 16 + frc) * 32 + q * 8;
#pragma unroll
    for (int n = 0; n < 4; ++n) bidx[n] = (wc * 64 + n * 16 + frc) * 40 + q * 8;

    floatx4 acc[4][4];
#pragma unroll
    for (int m = 0; m < 4; ++m)
#pragma unroll
        for (int n = 0; n < 4; ++n) acc[m][n] = floatx4{0.f, 0.f, 0.f, 0.f};

    unsigned held[16];

    __syncthreads();   // s_s ready

    // ---- prologue: stage A(phase 0) + full B(i-tile 0) ----
#pragma unroll
    for (int j = 0; j < 2; ++j)
        gload_lds16(asrc[j], &smA[0][(wid * 2 + j) * 512]);

#pragma unroll
    for (int sl = 0; sl < 8; ++sl) {
        const float* xp = xrow + (size_t)(sl * 4) * 4096;
        int i0 = sl * 4;
        float v0 = xp[0]         * s_s[i0];
        float v1 = xp[4096]      * s_s[i0 + 1];
        float v2 = xp[2 * 4096]  * s_s[i0 + 2];
        float v3 = xp[3 * 4096]  * s_s[i0 + 3];
        held[2 * sl]     = (unsigned)f2bfu(v0) | ((unsigned)f2bfu(v1) << 16);
        held[2 * sl + 1] = (unsigned)f2bfu(v2) | ((unsigned)f2bfu(v3) << 16);
    }
    *(uintx4*)(bg)      = uintx4{held[0],  held[1],  held[2],  held[3]};
    *(uintx4*)(bg + 8)  = uintx4{held[4],  held[5],  held[6],  held[7]};
    *(uintx4*)(bg + 16) = uintx4{held[8],  held[9],  held[10], held[11]};
    *(uintx4*)(bg + 24) = uintx4{held[12], held[13], held[14], held[15]};

    __syncthreads();   // drains A DMA (vmcnt) + B writes (lgkm)

    // ---- main loop: 16 i-tiles x 9 kpos ----
    for (int itile = 0; itile < 16; ++itile) {
        const float* xit = xrow + (size_t)(itile + 1) * 32 * 4096;
        int sbase = (itile + 1) * 32;
        int cur = itile & 1;                 // parity of phase 9*itile (9 odd)
#pragma unroll
        for (int kpos = 0; kpos < 9; ++kpos) {
            int abuf = (cur + kpos) & 1;
            // 1) issue A DMA for next phase
            if (!(itile == 15 && kpos == 8)) {
                int kN = (kpos == 8) ? 0 : kpos + 1;
                int iN = (kpos == 8) ? itile + 1 : itile;
                int off = kN * 512 + iN * 32;
#pragma unroll
                for (int j = 0; j < 2; ++j)
                    gload_lds16(asrc[j] + off, &smA[abuf ^ 1][(wid * 2 + j) * 512]);
            }
            // 2) B slice loads for next i-tile (4 i per phase, kpos 0..7)
            if (kpos < 8 && itile < 15) {
                const float* xp = xit + (size_t)(kpos * 4) * 4096;
                int i0 = sbase + kpos * 4;
                float v0 = xp[0]        * s_s[i0];
                float v1 = xp[4096]     * s_s[i0 + 1];
                float v2 = xp[2 * 4096] * s_s[i0 + 2];
                float v3 = xp[3 * 4096] * s_s[i0 + 3];
                held[2 * kpos]     = (unsigned)f2bfu(v0) | ((unsigned)f2bfu(v1) << 16);
                held[2 * kpos + 1] = (unsigned)f2bfu(v2) | ((unsigned)f2bfu(v3) << 16);
            }
            // 3) compute: 16 MFMA from A[abuf] and B (shifted by kpos)
            {
                int kh = kpos / 3, kw = kpos - kh * 3;
                int bo = (kh * 64 + kw) * 40;
                const unsigned short* A = smA[abuf];
                short8 af[4], bfr[4];
#pragma unroll
                for (int m = 0; m < 4; ++m) af[m] = *(const short8*)(A + aidx[m]);
#pragma unroll
                for (int n = 0; n < 4; ++n) bfr[n] = *(const short8*)(smB + bidx[n] + bo);
#pragma unroll
                for (int m = 0; m < 4; ++m)
#pragma unroll
                    for (int n = 0; n < 4; ++n)
                        acc[m][n] = __builtin_amdgcn_mfma_f32_16x16x32_bf16(af[m], bfr[n], acc[m][n], 0, 0, 0);
            }
            // 4) barriers / B-tile swap at i-tile boundary
            if (kpos == 8) {
                __syncthreads();             // everyone done reading smB + drains DMA
                if (itile < 15) {
                    *(uintx4*)(bg)      = uintx4{held[0],  held[1],  held[2],  held[3]};
                    *(uintx4*)(bg + 8)  = uintx4{held[4],  held[5],  held[6],  held[7]};
                    *(uintx4*)(bg + 16) = uintx4{held[8],  held[9],  held[10], held[11]};
                    *(uintx4*)(bg + 24) = uintx4{held[12], held[13], held[14], held[15]};
                }
                __syncthreads();             // B writes visible
            } else {
                __syncthreads();             // A DMA drained (vmcnt) + buffer handoff
            }
        }
    }

    // ---- epilogue: scale by WMC * d[b,o], store fp32 ----
    size_t outb = (size_t)b * 512 * NP;
#pragma unroll
    for (int m = 0; m < 4; ++m) {
#pragma unroll
        for (int r = 0; r < 4; ++r) {
            int o_l = wr * 64 + m * 16 + q * 4 + r;
            float scale = W_MUL_CONV * s_d[o_l];
            size_t rb = outb + (size_t)(oB + o_l) * NP + strip * 124 + wc * OW;
#pragma unroll
            for (int n = 0; n < 4; ++n) {
                int col = n * 16 + frc;
                if (col < OW) out[rb + col] = acc[m][n][r] * scale;
            }
        }
    }
}

// ---------------- launch ----------------
extern "C" void kernel_launch(void* const* d_in, const int* in_sizes, int n_in,
                              void* d_out, int out_size, void* d_ws, size_t ws_size,
                              hipStream_t stream) {
    const float* x  = (const float*)d_in[0];   // [16,512,64,64]
    const float* y  = (const float*)d_in[1];   // [16,512]
    const float* dw = (const float*)d_in[2];   // [512,512]
    const float* db = (const float*)d_in[3];   // [512]
    const float* w  = (const float*)d_in[4];   // [512,512,3,3]
    float* out = (float*)d_out;                // [16,512,62,62]

    char* ws = (char*)d_ws;
    float* s_  = (float*)ws;                               // 16*512 f32   (32 KB)
    float* d_  = (float*)(ws + 32768);                     // 16*512 f32   (32 KB)
    float* wsq = (float*)(ws + 65536);                     // 512*512 f32  (1 MB)
    unsigned short* wb = (unsigned short*)(ws + 65536 + 1048576);  // 512*9*512 bf16 (4.72 MB)

    emc_style_kernel<<<32, 256, 0, stream>>>(y, dw, db, s_);
    emc_wsq_kernel<<<1024, 256, 0, stream>>>(w, wsq);
    emc_demod_kernel<<<32, 256, 0, stream>>>(s_, wsq, d_);
    emc_wrepack_kernel<<<9216, 256, 0, stream>>>(w, wb);
    emc_conv_kernel<<<16 * 124, 256, 0, stream>>>(x, wb, s_, d_, out);
}

// Round 3
// 349.073 us; speedup vs baseline: 2.8879x; 1.1497x over previous
//
#include <hip/hip_runtime.h>
#include <hip/hip_bf16.h>

#define CIN 512
#define COUT 512
#define BATCH 16
#define NP 3844          // 62*62 output positions
#define OW 62

#define W_MUL_DENSE 0.044194173824159216f
#define W_MUL_CONV  0.014731391274719736f

using short8  = __attribute__((ext_vector_type(8))) short;
using floatx4 = __attribute__((ext_vector_type(4))) float;
using uintx4  = __attribute__((ext_vector_type(4))) unsigned int;

__device__ __forceinline__ unsigned short f2bfu(float f) {
    unsigned u = __builtin_bit_cast(unsigned, f);
    u += 0x7FFFu + ((u >> 16) & 1u);   // round-to-nearest-even
    return (unsigned short)(u >> 16);
}

__device__ __forceinline__ void gload_lds16(const void* g, void* l) {
    __builtin_amdgcn_global_load_lds(
        (const __attribute__((address_space(1))) void*)g,
        (__attribute__((address_space(3))) void*)l, 16, 0, 0);
}

// ---------------- prep kernels ----------------

__global__ void emc_style_kernel(const float* __restrict__ y, const float* __restrict__ dw,
                                 const float* __restrict__ db, float* __restrict__ s) {
    int idx = blockIdx.x * 256 + threadIdx.x;       // 16*512
    int b = idx >> 9, c = idx & 511;
    const float4* yb = (const float4*)(y + b * 512);
    const float4* wc = (const float4*)(dw + c * 512);
    float acc = 0.f;
#pragma unroll 4
    for (int l = 0; l < 128; ++l) {
        float4 a = yb[l], w4 = wc[l];
        acc += a.x * w4.x + a.y * w4.y + a.z * w4.z + a.w * w4.w;
    }
    s[idx] = acc * W_MUL_DENSE + db[c];
}

__global__ void emc_wsq_kernel(const float* __restrict__ w, float* __restrict__ wsq) {
    int idx = blockIdx.x * 256 + threadIdx.x;       // 512*512
    const float* p = w + (size_t)idx * 9;
    float a = 0.f;
#pragma unroll
    for (int j = 0; j < 9; ++j) a += p[j] * p[j];
    wsq[idx] = a;
}

__global__ void emc_demod_kernel(const float* __restrict__ s, const float* __restrict__ wsq,
                                 float* __restrict__ d) {
    int idx = blockIdx.x * 256 + threadIdx.x;       // 16*512
    int b = idx >> 9, o = idx & 511;
    const float4* sb = (const float4*)(s + b * 512);
    const float4* wo = (const float4*)(wsq + o * 512);
    float acc = 0.f;
#pragma unroll 4
    for (int l = 0; l < 128; ++l) {
        float4 a = sb[l], c = wo[l];
        acc += a.x * a.x * c.x + a.y * a.y * c.y + a.z * a.z * c.z + a.w * a.w * c.w;
    }
    d[idx] = rsqrtf(W_MUL_CONV * W_MUL_CONV * acc + 1e-8f);
}

// wb[(o*9+kpos)*512 + i] = bf16(w[(o*512+i)*9 + kpos])  (linear, K-contig in i per kpos)
__global__ void emc_wrepack_kernel(const float* __restrict__ w, unsigned short* __restrict__ wb) {
    int idx = blockIdx.x * 256 + threadIdx.x;       // 512*9*512
    int i = idx & 511;
    int r = idx >> 9;
    int kpos = r % 9;
    int o = r / 9;
    wb[idx] = f2bfu(w[(size_t)(o * 512 + i) * 9 + kpos]);
}

// ---------------- main conv kernel ----------------
// Tile: BM=256 (o) x strip of 2 output rows (124 p, padded 128).
// B (x-halo): [4 rows][64 cols][32 i] bf16 in 80B granules, staged once per i-tile,
//   reused by all 9 kpos via shifted reads.
// A (weights): 256x32 bf16 per (kpos,i-tile), double-buffered via global_load_lds
//   width-16. LDS dest linear; k-slot XOR-swizzled on the GLOBAL source and on the
//   read offset (slot = q ^ ((row>>1)&3)) so quarter-wave ds_read_b128 hits 8
//   distinct start-bank groups (2-way = free) instead of 2 (8-way conflict).

__global__ __launch_bounds__(256, 2) void emc_conv_kernel(
    const float* __restrict__ x, const unsigned short* __restrict__ wb,
    const float* __restrict__ sv, const float* __restrict__ dv,
    float* __restrict__ out) {

    __shared__ __align__(16) unsigned short smA[2][256 * 32];   // 2 x 16 KB
    __shared__ __align__(16) unsigned short smB[260 * 40];      // 20.8 KB
    __shared__ float s_s[512];
    __shared__ float s_d[256];

    // bijective XCD swizzle (gridDim = 992, 992 % 8 == 0)
    int orig = blockIdx.x;
    int cpx = gridDim.x >> 3;
    int bid = (orig & 7) * cpx + (orig >> 3);

    int b = bid / 62;               // 62 blocks per batch = 2 o-tiles * 31 strips
    int t = bid - b * 62;
    int ot = t & 1;
    int strip = t >> 1;
    int oB = ot * 256;
    int r0 = strip * 2;

    int tid = threadIdx.x;
    int lane = tid & 63;
    int wid = tid >> 6;

    s_s[tid]       = sv[b * 512 + tid];
    s_s[tid + 256] = sv[b * 512 + 256 + tid];
    s_d[tid]       = dv[b * 512 + oB + tid];

    // ---- B staging ids: thread owns (input row sr, col sc) ----
    int sc = tid & 63;
    int sr = tid >> 6;
    const float* xrow = x + (size_t)b * (512 * 4096) + (r0 + sr) * 64 + sc;
    unsigned short* bg = smB + (sr * 64 + sc) * 40;

    // ---- A DMA ids: wave wid covers rows [wid*64, wid*64+64), 4 instrs ----
    const unsigned short* asrc[4];
    int adst[4];
#pragma unroll
    for (int j = 0; j < 4; ++j) {
        int row = wid * 64 + j * 16 + (lane >> 2);
        asrc[j] = wb + (size_t)(oB + row) * 4608 + (((lane & 3) ^ ((row >> 1) & 3)) << 3);
        adst[j] = (wid * 64 + j * 16) * 32;
    }

    // ---- compute ids ----
    int frc = lane & 15, q = lane >> 4;
    int wr = wid >> 1, wc = wid & 1;    // wr: o-half (128 rows), wc: output row in strip
    int aidx[8], bidx[4];
#pragma unroll
    for (int m = 0; m < 8; ++m) {
        int row = wr * 128 + m * 16 + frc;
        aidx[m] = row * 32 + ((q ^ ((row >> 1) & 3)) << 3);
    }
#pragma unroll
    for (int n = 0; n < 4; ++n) bidx[n] = (wc * 64 + n * 16 + frc) * 40 + q * 8;

    floatx4 acc[8][4];
#pragma unroll
    for (int m = 0; m < 8; ++m)
#pragma unroll
        for (int n = 0; n < 4; ++n) acc[m][n] = floatx4{0.f, 0.f, 0.f, 0.f};

    unsigned held[16];

    __syncthreads();   // s_s ready

    // ---- prologue: stage A(phase 0) + full B(i-tile 0) ----
#pragma unroll
    for (int j = 0; j < 4; ++j)
        gload_lds16(asrc[j], &smA[0][adst[j]]);

#pragma unroll
    for (int sl = 0; sl < 8; ++sl) {
        const float* xp = xrow + (size_t)(sl * 4) * 4096;
        int i0 = sl * 4;
        float v0 = xp[0]         * s_s[i0];
        float v1 = xp[4096]      * s_s[i0 + 1];
        float v2 = xp[2 * 4096]  * s_s[i0 + 2];
        float v3 = xp[3 * 4096]  * s_s[i0 + 3];
        held[2 * sl]     = (unsigned)f2bfu(v0) | ((unsigned)f2bfu(v1) << 16);
        held[2 * sl + 1] = (unsigned)f2bfu(v2) | ((unsigned)f2bfu(v3) << 16);
    }
    *(uintx4*)(bg)      = uintx4{held[0],  held[1],  held[2],  held[3]};
    *(uintx4*)(bg + 8)  = uintx4{held[4],  held[5],  held[6],  held[7]};
    *(uintx4*)(bg + 16) = uintx4{held[8],  held[9],  held[10], held[11]};
    *(uintx4*)(bg + 24) = uintx4{held[12], held[13], held[14], held[15]};

    __syncthreads();   // drains A DMA (vmcnt) + B writes (lgkm)

    // ---- main loop: 16 i-tiles x 9 kpos ----
    for (int itile = 0; itile < 16; ++itile) {
        const float* xit = xrow + (size_t)(itile + 1) * 32 * 4096;
        int sbase = (itile + 1) * 32;
        int cur = itile & 1;
#pragma unroll
        for (int kpos = 0; kpos < 9; ++kpos) {
            int abuf = (cur + kpos) & 1;
            // 1) issue A DMA for next phase (overlaps this phase's compute)
            if (!(itile == 15 && kpos == 8)) {
                int kN = (kpos == 8) ? 0 : kpos + 1;
                int iN = (kpos == 8) ? itile + 1 : itile;
                int off = kN * 512 + iN * 32;
#pragma unroll
                for (int j = 0; j < 4; ++j)
                    gload_lds16(asrc[j] + off, &smA[abuf ^ 1][adst[j]]);
            }
            // 2) B slice loads for next i-tile (4 i per phase, kpos 0..7)
            if (kpos < 8 && itile < 15) {
                const float* xp = xit + (size_t)(kpos * 4) * 4096;
                int i0 = sbase + kpos * 4;
                float v0 = xp[0]        * s_s[i0];
                float v1 = xp[4096]     * s_s[i0 + 1];
                float v2 = xp[2 * 4096] * s_s[i0 + 2];
                float v3 = xp[3 * 4096] * s_s[i0 + 3];
                held[2 * kpos]     = (unsigned)f2bfu(v0) | ((unsigned)f2bfu(v1) << 16);
                held[2 * kpos + 1] = (unsigned)f2bfu(v2) | ((unsigned)f2bfu(v3) << 16);
            }
            // 3) compute: 32 MFMA from A[abuf] and B (shifted by kpos)
            {
                int kh = kpos / 3, kw = kpos - kh * 3;
                int bo = (kh * 64 + kw) * 40;
                const unsigned short* A = smA[abuf];
                short8 bfr[4];
#pragma unroll
                for (int n = 0; n < 4; ++n) bfr[n] = *(const short8*)(smB + bidx[n] + bo);
#pragma unroll
                for (int mh = 0; mh < 2; ++mh) {
                    short8 af[4];
#pragma unroll
                    for (int mm = 0; mm < 4; ++mm) af[mm] = *(const short8*)(A + aidx[mh * 4 + mm]);
#pragma unroll
                    for (int mm = 0; mm < 4; ++mm)
#pragma unroll
                        for (int n = 0; n < 4; ++n)
                            acc[mh * 4 + mm][n] = __builtin_amdgcn_mfma_f32_16x16x32_bf16(
                                af[mm], bfr[n], acc[mh * 4 + mm][n], 0, 0, 0);
                }
            }
            // 4) barriers / B-tile swap at i-tile boundary
            if (kpos == 8) {
                __syncthreads();             // everyone done reading smB + drains DMA
                if (itile < 15) {
                    *(uintx4*)(bg)      = uintx4{held[0],  held[1],  held[2],  held[3]};
                    *(uintx4*)(bg + 8)  = uintx4{held[4],  held[5],  held[6],  held[7]};
                    *(uintx4*)(bg + 16) = uintx4{held[8],  held[9],  held[10], held[11]};
                    *(uintx4*)(bg + 24) = uintx4{held[12], held[13], held[14], held[15]};
                }
                __syncthreads();             // B writes visible
            } else {
                __syncthreads();             // A DMA drained + buffer handoff
            }
        }
    }

    // ---- epilogue: scale by WMC * d[b,o], store fp32 ----
    size_t outb = (size_t)b * 512 * NP;
#pragma unroll
    for (int m = 0; m < 8; ++m) {
#pragma unroll
        for (int r = 0; r < 4; ++r) {
            int o_l = wr * 128 + m * 16 + q * 4 + r;
            float scale = W_MUL_CONV * s_d[o_l];
            size_t rb = outb + (size_t)(oB + o_l) * NP + strip * 124 + wc * OW;
#pragma unroll
            for (int n = 0; n < 4; ++n) {
                int col = n * 16 + frc;
                if (col < OW) out[rb + col] = acc[m][n][r] * scale;
            }
        }
    }
}

// ---------------- launch ----------------
extern "C" void kernel_launch(void* const* d_in, const int* in_sizes, int n_in,
                              void* d_out, int out_size, void* d_ws, size_t ws_size,
                              hipStream_t stream) {
    const float* x  = (const float*)d_in[0];   // [16,512,64,64]
    const float* y  = (const float*)d_in[1];   // [16,512]
    const float* dw = (const float*)d_in[2];   // [512,512]
    const float* db = (const float*)d_in[3];   // [512]
    const float* w  = (const float*)d_in[4];   // [512,512,3,3]
    float* out = (float*)d_out;                // [16,512,62,62]

    char* ws = (char*)d_ws;
    float* s_  = (float*)ws;                               // 16*512 f32   (32 KB)
    float* d_  = (float*)(ws + 32768);                     // 16*512 f32   (32 KB)
    float* wsq = (float*)(ws + 65536);                     // 512*512 f32  (1 MB)
    unsigned short* wb = (unsigned short*)(ws + 65536 + 1048576);  // 512*9*512 bf16 (4.72 MB)

    emc_style_kernel<<<32, 256, 0, stream>>>(y, dw, db, s_);
    emc_wsq_kernel<<<1024, 256, 0, stream>>>(w, wsq);
    emc_demod_kernel<<<32, 256, 0, stream>>>(s_, wsq, d_);
    emc_wrepack_kernel<<<9216, 256, 0, stream>>>(w, wb);
    emc_conv_kernel<<<16 * 62, 256, 0, stream>>>(x, wb, s_, d_, out);
}